// Round 2
// baseline (581.259 us; speedup 1.0000x reference)
//
#include <hip/hip_runtime.h>
#include <math.h>

#define N    257     // state dim
#define AP   258     // doubles per A row (cols 0..256 = S, col 257 = rhs)
#define MM   128     // rotation pairs
#define LL   512     // seq length
#define BB   4       // batch
#define NB   32      // panel width

// ws byte layout:
#define A_BYTE    0         // double[257*258] = 530448
#define W0_BYTE   530448    // float[257]  -> ends 531476
#define CXY_BYTE  531488    // float[4096] -> ends 547872
#define PW_BYTE   547904    // double[32*257] = 65792 -> ends 613696
#define U12_BYTE  613696    // double[32*226] = 57856 -> ends 671552
// total ~672 KB

// ---------------------------------------------------------------------------
// prefix sums of x[b,:,comp]: theta[b,l,m] = cx[b,l]*om0[m] + cy[b,l]*om1[m]
// ---------------------------------------------------------------------------
__global__ __launch_bounds__(512) void scan_kernel(const float* __restrict__ x,
                                                   void* __restrict__ wsv) {
  const int tid  = threadIdx.x;
  const int wave = tid >> 6, lane = tid & 63;
  const int b    = wave >> 1, comp = wave & 1;

  const float* xp = x + ((size_t)b * LL) * 2 + comp;
  double loc[8];
  double run = 0.0;
  #pragma unroll
  for (int e = 0; e < 8; ++e) {
    run += (double)xp[(lane * 8 + e) * 2];
    loc[e] = run;
  }
  double tot = run;
  #pragma unroll
  for (int off = 1; off < 64; off <<= 1) {
    const double o = __shfl_up(tot, off);
    if (lane >= off) tot += o;
  }
  const double excl = tot - run;
  float* cp = (float*)((char*)wsv + CXY_BYTE) + ((size_t)b * LL) * 2 + comp;
  #pragma unroll
  for (int e = 0; e < 8; ++e)
    cp[(lane * 8 + e) * 2] = (float)(excl + loc[e]);
}

// ---------------------------------------------------------------------------
// stage A = [S | z0] in fp64, grid-wide
// ---------------------------------------------------------------------------
__global__ __launch_bounds__(256) void stage_kernel(const float* __restrict__ S,
                                                    const float* __restrict__ z0,
                                                    void* __restrict__ wsv) {
  double* A = (double*)((char*)wsv + A_BYTE);
  const int idx = blockIdx.x * 256 + threadIdx.x;
  if (idx < N * N) {
    const int i = idx / N, j = idx - i * N;
    A[i * AP + j] = (double)S[idx];
  } else {
    const int r = idx - N * N;
    if (r < N) A[r * AP + N] = (double)z0[r];
  }
}

// ---------------------------------------------------------------------------
// panel factor, round-2 restructure: unified row-parallel Jordan elimination.
//
// Old design (53.5 us/dispatch): wave0 shfl factorization + M01 right-solve +
// per-thread register triangular passes — ~60 KB of fully-unrolled fp64 code,
// 500-deep dependent chains, 1 block / 2 waves per SIMD -> pure latency, ~35
// cy/instr. The M01 right-solve, the below-panel elimination, and the L21
// factor computation are all the SAME recurrence:
//     f[i][j] = (P[i][j] - sum_{t<j} f[i][t]*U[t][j]) / U[j][j]
// so compute them for ALL rows at once: panel (257x32) lives in LDS, thread i
// owns row i, 32 steps of {f = P[i][j]*pinv; row -= f*pivot_row; P[i][j]=f}
// with one barrier per step. Pivot rows freeze in place -> F11 = L11\U11.
// U12 solve is per-thread-owns-a-column over LDS (zero barriers), with the 32
// global row loads prefetched at kernel start. All loops rolled: small code,
// no per-thread arrays, no scratch ambiguity.
// ---------------------------------------------------------------------------
__global__ __launch_bounds__(512) void panel_factor_kernel(void* __restrict__ wsv,
                                                           int k0) {
  __shared__ double P[N][NB + 1];         // 257*33*8 = 67848 B  (panel columns)
  __shared__ double u_s[226][NB + 1];     // 226*33*8 = 59664 B  (U12 columns)
  __shared__ double pinv[NB];
  double* A    = (double*)((char*)wsv + A_BYTE);
  double* Pw   = (double*)((char*)wsv + PW_BYTE);
  double* U12w = (double*)((char*)wsv + U12_BYTE);
  const int tid = threadIdx.x;
  const int ct  = k0 + NB;
  const int tc2 = 258 - ct;               // trailing cols incl rhs

  // ---- stage panel A[0:N, k0:ct) -> P (coalesced double2) ----
  for (int flat = tid; flat < N * 16; flat += 512) {
    const int i  = flat >> 4;
    const int cp = (flat & 15) * 2;
    const double2 v = *(const double2*)&A[(size_t)i * AP + k0 + cp];
    P[i][cp]     = v.x;
    P[i][cp + 1] = v.y;
  }
  // ---- prefetch pivot rows' trailing block -> u_s (own column per thread) ----
  if (tid < tc2) {
    for (int jr = 0; jr < NB; ++jr)
      u_s[tid][jr] = A[(size_t)(k0 + jr) * AP + ct + tid];
  }
  __syncthreads();
  if (tid == 0) pinv[0] = 1.0 / P[k0][0];
  __syncthreads();

  // ---- 32-step row-parallel Jordan elimination over panel columns ----
  for (int j = 0; j < NB; ++j) {
    const int pr = k0 + j;
    if (tid < N && (tid < k0 || tid > pr)) {   // frozen: earlier pivot rows + pr
      const double f = P[tid][j] * pinv[j];
      #pragma unroll 4
      for (int j2 = j + 1; j2 < NB; ++j2)
        P[tid][j2] -= f * P[pr][j2];
      P[tid][j] = f;
      if (tid == pr + 1 && j + 1 < NB)
        pinv[j + 1] = 1.0 / P[tid][j + 1];     // next pivot's reciprocal, pre-barrier
    }
    __syncthreads();
  }

  // ---- publish factors (all non-pivot rows; pivot-band garbage is unread) ----
  if (tid < N) {
    for (int t = 0; t < NB; ++t)
      Pw[(size_t)t * N + tid] = P[tid][t];
  }
  // ---- publish F11 = L11\U11 block back to A (finish kernel reads U) ----
  for (int flat = tid; flat < NB * NB; flat += 512) {
    const int r = flat >> 5, c = flat & 31;
    A[(size_t)(k0 + r) * AP + k0 + c] = P[k0 + r][c];
  }

  // ---- U12 forward solve: thread owns column tid, fully local in u_s ----
  if (tid < tc2) {
    for (int jr = 1; jr < NB; ++jr) {
      double vv = u_s[tid][jr];
      #pragma unroll 4
      for (int t = 0; t < jr; ++t)
        vv -= P[k0 + jr][t] * u_s[tid][t];   // P[k0+jr][t<jr] = L11 factors
      u_s[tid][jr] = vv;
    }
    for (int jr = 0; jr < NB; ++jr) {
      const double vv = u_s[tid][jr];
      U12w[jr * 226 + tid] = vv;
      A[(size_t)(k0 + jr) * AP + ct + tid] = vv;
    }
  }
}

// ---------------------------------------------------------------------------
// panel update (grid-parallel Jordan rank-32 GEMM):
//   rows R = [0,k0) U [ct,N)  (225 rows, R-index rb; gr = rb<k0 ? rb : rb+32)
//   cols [ct, 258): A[gr][c] -= sum_t Pw[t][gr] * U12[t][c-ct]
// block tile = 32 rows x 64 cols; thread tile = 2x4.
// ---------------------------------------------------------------------------
__global__ __launch_bounds__(256) void panel_update_kernel(void* __restrict__ wsv,
                                                           int k0, int tc2) {
  __shared__ double Pl[NB][NB + 1];
  __shared__ __align__(16) double Ul[NB][66];
  double* A = (double*)((char*)wsv + A_BYTE);
  const double* Pw   = (const double*)((const char*)wsv + PW_BYTE);
  const double* U12w = (const double*)((const char*)wsv + U12_BYTE);
  const int tid = threadIdx.x;
  const int ct  = k0 + NB;
  const int rb0 = blockIdx.x * 32;
  const int c0  = blockIdx.y * 64;

  for (int i = tid; i < 32 * 32; i += 256) {
    const int t = i >> 5, rr = i & 31;
    const int rb = rb0 + rr;
    const int gr = (rb < k0) ? rb : rb + NB;
    Pl[t][rr] = (rb < 225) ? Pw[t * N + gr] : 0.0;
  }
  for (int i = tid; i < 32 * 64; i += 256) {
    const int t = i >> 6, c = i & 63;
    Ul[t][c] = (c0 + c < tc2) ? U12w[t * 226 + c0 + c] : 0.0;
  }
  __syncthreads();

  const int tr  = tid >> 4;          // 0..15 -> rows tr*2 .. +1
  const int tcx = (tid & 15) * 4;    // cols tcx .. +3
  double acc[2][4];
  #pragma unroll
  for (int rr = 0; rr < 2; ++rr) {
    const int rb = rb0 + tr * 2 + rr;
    const int gr = (rb < k0) ? rb : rb + NB;
    #pragma unroll
    for (int c = 0; c < 4; ++c)
      acc[rr][c] = (rb < 225 && (c0 + tcx + c) < tc2)
                 ? A[gr * AP + ct + c0 + tcx + c] : 0.0;
  }
  #pragma unroll
  for (int t = 0; t < NB; ++t) {
    const double p0 = Pl[t][tr * 2], p1 = Pl[t][tr * 2 + 1];
    const double2 u0 = *(const double2*)&Ul[t][tcx];
    const double2 u1 = *(const double2*)&Ul[t][tcx + 2];
    acc[0][0] -= p0 * u0.x; acc[0][1] -= p0 * u0.y;
    acc[0][2] -= p0 * u1.x; acc[0][3] -= p0 * u1.y;
    acc[1][0] -= p1 * u0.x; acc[1][1] -= p1 * u0.y;
    acc[1][2] -= p1 * u1.x; acc[1][3] -= p1 * u1.y;
  }
  #pragma unroll
  for (int rr = 0; rr < 2; ++rr) {
    const int rb = rb0 + tr * 2 + rr;
    const int gr = (rb < k0) ? rb : rb + NB;
    #pragma unroll
    for (int c = 0; c < 4; ++c)
      if (rb < 225 && (c0 + tcx + c) < tc2)
        A[gr * AP + ct + c0 + tcx + c] = acc[rr][c];
  }
}

// ---------------------------------------------------------------------------
// finish: x256 division, then 8 independent per-panel 32-step back-substs
// ---------------------------------------------------------------------------
__global__ __launch_bounds__(256) void finish_kernel(void* __restrict__ wsv) {
  __shared__ double xs[N];
  __shared__ double rr[256];
  double* A   = (double*)((char*)wsv + A_BYTE);
  float*  w0f = (float*)((char*)wsv + W0_BYTE);
  const int tid = threadIdx.x;
  if (tid == 0) xs[256] = A[256 * AP + 257] / A[256 * AP + 256];
  __syncthreads();
  const double x256 = xs[256];
  rr[tid] = A[tid * AP + 257] - A[tid * AP + 256] * x256;
  __syncthreads();
  const int fk0 = tid & ~31;
  const int fs  = tid & 31;
  for (int j = 31; j >= 0; --j) {
    if (fs == j) xs[fk0 + j] = rr[fk0 + j] / A[(fk0 + j) * AP + (fk0 + j)];
    __syncthreads();
    if (fs < j) rr[fk0 + fs] -= A[(fk0 + fs) * AP + (fk0 + j)] * xs[fk0 + j];
    __syncthreads();
  }
  w0f[tid] = (float)xs[tid];
  if (tid == 0) w0f[256] = (float)xs[256];
}

// ---------------------------------------------------------------------------
// combine: out[(b,l), i] = sum_d S[i,d] * W[(b,l), d]
// ---------------------------------------------------------------------------
#define NL 8
__global__ __launch_bounds__(320) void combine_kernel(const float* __restrict__ S,
                                                      const float* __restrict__ om,
                                                      const void* __restrict__ wsv,
                                                      float* __restrict__ out) {
  const int tid = threadIdx.x;
  const int b  = blockIdx.y;
  const int l0 = blockIdx.x * NL;
  const float* w0  = (const float*)((const char*)wsv + W0_BYTE);
  const float* cxy = (const float*)((const char*)wsv + CXY_BYTE);
  __shared__ float Wl[NL][N];
  __shared__ float omsh[2 * MM];
  __shared__ float cxs[NL], cys[NL];

  for (int idx = tid; idx < 2 * MM; idx += 320) omsh[idx] = om[idx];
  if (tid < NL) {
    cxs[tid] = cxy[((size_t)(b * LL) + l0 + tid) * 2];
    cys[tid] = cxy[((size_t)(b * LL) + l0 + tid) * 2 + 1];
  }
  __syncthreads();

  for (int idx = tid; idx < NL * N; idx += 320) {
    const int r = idx / N;
    const int d = idx - r * N;
    float v;
    if (d == 0) {
      v = w0[0];
    } else {
      const int m = (d - 1) >> 1;
      const int pq = 2 * m + 1;
      const float t = cxs[r] * omsh[2 * m] + cys[r] * omsh[2 * m + 1];
      float s, c;
      sincosf(t, &s, &c);
      const float a0 = w0[pq], a1 = w0[pq + 1];
      v = (d & 1) ? (c * a0 - s * a1) : (s * a0 + c * a1);
    }
    Wl[r][d] = v;
  }
  __syncthreads();

  const int i = tid;
  if (i < N) {
    const float* Si = S + (size_t)i * N;
    float acc[NL];
    #pragma unroll
    for (int r = 0; r < NL; ++r) acc[r] = 0.0f;
    #pragma unroll 4
    for (int d = 0; d < N; ++d) {
      const float sv = Si[d];
      #pragma unroll
      for (int r = 0; r < NL; ++r) acc[r] += sv * Wl[r][d];
    }
    const size_t base = (size_t)(b * LL + l0) * N + i;
    #pragma unroll
    for (int r = 0; r < NL; ++r) out[base + (size_t)r * N] = acc[r];
    if (l0 + NL == LL) {
      out[(size_t)BB * LL * N + (size_t)b * N + i] = acc[NL - 1];
    }
  }
}

extern "C" void kernel_launch(void* const* d_in, const int* in_sizes, int n_in,
                              void* d_out, int out_size, void* d_ws, size_t ws_size,
                              hipStream_t stream) {
  const float* x  = (const float*)d_in[0];   // (B, L, 2)
  const float* z0 = (const float*)d_in[1];   // (D,)
  const float* om = (const float*)d_in[2];   // (M, 2)
  const float* S  = (const float*)d_in[3];   // (D, D)
  float* out = (float*)d_out;                // outputs (B,L,D) then z_final (B,D)

  hipLaunchKernelGGL(scan_kernel,  dim3(1),   dim3(512), 0, stream, x, d_ws);
  hipLaunchKernelGGL(stage_kernel, dim3(260), dim3(256), 0, stream, S, z0, d_ws);
  for (int p = 0; p < 8; ++p) {
    const int k0  = p * NB;
    const int tc2 = 258 - (k0 + NB);
    hipLaunchKernelGGL(panel_factor_kernel, dim3(1), dim3(512), 0, stream, d_ws, k0);
    hipLaunchKernelGGL(panel_update_kernel, dim3(8, (tc2 + 63) / 64), dim3(256),
                       0, stream, d_ws, k0, tc2);
  }
  hipLaunchKernelGGL(finish_kernel, dim3(1), dim3(256), 0, stream, d_ws);
  hipLaunchKernelGGL(combine_kernel, dim3(LL / NL, BB), dim3(320), 0, stream, S, om, d_ws, out);
}

// Round 3
// 486.075 us; speedup vs baseline: 1.1958x; 1.1958x over previous
//
#include <hip/hip_runtime.h>
#include <math.h>

#define N    257     // state dim
#define AP   258     // doubles per A row (cols 0..256 = S, col 257 = rhs)
#define MM   128     // rotation pairs
#define LL   512     // seq length
#define BB   4       // batch
#define NB   32      // panel width

// ws byte layout:
#define A_BYTE    0         // double[257*258] = 530448
#define W0_BYTE   530448    // float[257]  -> ends 531476
#define CXY_BYTE  531488    // float[4096] -> ends 547872
#define PW_BYTE   547904    // double[32*257] = 65792 -> ends 613696
#define U12_BYTE  613696    // double[32*226] = 57856 -> ends 671552
// total ~672 KB

// ---------------------------------------------------------------------------
// prefix sums of x[b,:,comp]: theta[b,l,m] = cx[b,l]*om0[m] + cy[b,l]*om1[m]
// ---------------------------------------------------------------------------
__global__ __launch_bounds__(512) void scan_kernel(const float* __restrict__ x,
                                                   void* __restrict__ wsv) {
  const int tid  = threadIdx.x;
  const int wave = tid >> 6, lane = tid & 63;
  const int b    = wave >> 1, comp = wave & 1;

  const float* xp = x + ((size_t)b * LL) * 2 + comp;
  double loc[8];
  double run = 0.0;
  #pragma unroll
  for (int e = 0; e < 8; ++e) {
    run += (double)xp[(lane * 8 + e) * 2];
    loc[e] = run;
  }
  double tot = run;
  #pragma unroll
  for (int off = 1; off < 64; off <<= 1) {
    const double o = __shfl_up(tot, off);
    if (lane >= off) tot += o;
  }
  const double excl = tot - run;
  float* cp = (float*)((char*)wsv + CXY_BYTE) + ((size_t)b * LL) * 2 + comp;
  #pragma unroll
  for (int e = 0; e < 8; ++e)
    cp[(lane * 8 + e) * 2] = (float)(excl + loc[e]);
}

// ---------------------------------------------------------------------------
// stage A = [S | z0] in fp64, grid-wide
// ---------------------------------------------------------------------------
__global__ __launch_bounds__(256) void stage_kernel(const float* __restrict__ S,
                                                    const float* __restrict__ z0,
                                                    void* __restrict__ wsv) {
  double* A = (double*)((char*)wsv + A_BYTE);
  const int idx = blockIdx.x * 256 + threadIdx.x;
  if (idx < N * N) {
    const int i = idx / N, j = idx - i * N;
    A[i * AP + j] = (double)S[idx];
  } else {
    const int r = idx - N * N;
    if (r < N) A[r * AP + N] = (double)z0[r];
  }
}

// ---------------------------------------------------------------------------
// panel factor, round-3: same row-parallel Jordan as round 2, but with BOTH
// triangular nests fully statically unrolled.
//
// Round-2 evidence: dur 49.8us, VALUBusy ~11% on the active CU -> 89% stall.
// The rolled inner loops (runtime trip count) force per-element
// ds_read -> lgkmcnt(0) -> fma -> ds_write sequences: ~100cy LDS latency per
// element, 528 elements in the Jordan nest + 528 in the U12 nest = ~40us of
// pure latency. With static unrolling the compiler batches the ds_reads and
// uses incremental lgkmcnt(N) waits (m97 asm behavior), so latency is paid
// once per STEP, not once per element:
//   Jordan: 32 steps x ~450cy  ~= 6us
//   U12:    32 steps x ~250cy  ~= 3us
// ---------------------------------------------------------------------------
__global__ __launch_bounds__(512) void panel_factor_kernel(void* __restrict__ wsv,
                                                           int k0) {
  __shared__ double P[N][NB + 1];         // 257*33*8 = 67848 B  (panel columns)
  __shared__ double u_s[226][NB + 1];     // 226*33*8 = 59664 B  (U12 columns)
  __shared__ double pinv[NB];
  double* A    = (double*)((char*)wsv + A_BYTE);
  double* Pw   = (double*)((char*)wsv + PW_BYTE);
  double* U12w = (double*)((char*)wsv + U12_BYTE);
  const int tid = threadIdx.x;
  const int ct  = k0 + NB;
  const int tc2 = 258 - ct;               // trailing cols incl rhs

  // ---- stage panel A[0:N, k0:ct) -> P (coalesced double2) ----
  for (int flat = tid; flat < N * 16; flat += 512) {
    const int i  = flat >> 4;
    const int cp = (flat & 15) * 2;
    const double2 v = *(const double2*)&A[(size_t)i * AP + k0 + cp];
    P[i][cp]     = v.x;
    P[i][cp + 1] = v.y;
  }
  // ---- prefetch pivot rows' trailing block -> u_s (own column per thread) ----
  if (tid < tc2) {
    #pragma unroll
    for (int jr = 0; jr < NB; ++jr)
      u_s[tid][jr] = A[(size_t)(k0 + jr) * AP + ct + tid];
  }
  __syncthreads();
  if (tid == 0) pinv[0] = 1.0 / P[k0][0];
  __syncthreads();

  // ---- 32-step row-parallel Jordan elimination, FULLY UNROLLED ----
  #pragma unroll
  for (int j = 0; j < NB; ++j) {
    const int pr = k0 + j;
    if (tid < N && (tid < k0 || tid > pr)) {   // frozen: earlier pivot rows + pr
      const double f = P[tid][j] * pinv[j];
      #pragma unroll
      for (int j2 = j + 1; j2 < NB; ++j2)
        P[tid][j2] -= f * P[pr][j2];
      P[tid][j] = f;
      if (tid == pr + 1 && j + 1 < NB)
        pinv[j + 1] = 1.0 / P[tid][j + 1];     // next pivot's reciprocal, pre-barrier
    }
    __syncthreads();
  }

  // ---- publish factors (all non-pivot rows; pivot-band garbage is unread) ----
  if (tid < N) {
    #pragma unroll
    for (int t = 0; t < NB; ++t)
      Pw[(size_t)t * N + tid] = P[tid][t];
  }
  // ---- publish F11 = L11\U11 block back to A (finish kernel reads U) ----
  for (int flat = tid; flat < NB * NB; flat += 512) {
    const int r = flat >> 5, c = flat & 31;
    A[(size_t)(k0 + r) * AP + k0 + c] = P[k0 + r][c];
  }

  // ---- U12 forward solve: thread owns column tid, FULLY UNROLLED ----
  if (tid < tc2) {
    #pragma unroll
    for (int jr = 1; jr < NB; ++jr) {
      double vv = u_s[tid][jr];
      #pragma unroll
      for (int t = 0; t < jr; ++t)
        vv -= P[k0 + jr][t] * u_s[tid][t];   // P[k0+jr][t<jr] = L11 factors
      u_s[tid][jr] = vv;
    }
    #pragma unroll
    for (int jr = 0; jr < NB; ++jr) {
      const double vv = u_s[tid][jr];
      U12w[jr * 226 + tid] = vv;
      A[(size_t)(k0 + jr) * AP + ct + tid] = vv;
    }
  }
}

// ---------------------------------------------------------------------------
// panel update (grid-parallel Jordan rank-32 GEMM):
//   rows R = [0,k0) U [ct,N)  (225 rows, R-index rb; gr = rb<k0 ? rb : rb+32)
//   cols [ct, 258): A[gr][c] -= sum_t Pw[t][gr] * U12[t][c-ct]
// block tile = 32 rows x 64 cols; thread tile = 2x4.
// ---------------------------------------------------------------------------
__global__ __launch_bounds__(256) void panel_update_kernel(void* __restrict__ wsv,
                                                           int k0, int tc2) {
  __shared__ double Pl[NB][NB + 1];
  __shared__ __align__(16) double Ul[NB][66];
  double* A = (double*)((char*)wsv + A_BYTE);
  const double* Pw   = (const double*)((const char*)wsv + PW_BYTE);
  const double* U12w = (const double*)((const char*)wsv + U12_BYTE);
  const int tid = threadIdx.x;
  const int ct  = k0 + NB;
  const int rb0 = blockIdx.x * 32;
  const int c0  = blockIdx.y * 64;

  for (int i = tid; i < 32 * 32; i += 256) {
    const int t = i >> 5, rr = i & 31;
    const int rb = rb0 + rr;
    const int gr = (rb < k0) ? rb : rb + NB;
    Pl[t][rr] = (rb < 225) ? Pw[t * N + gr] : 0.0;
  }
  for (int i = tid; i < 32 * 64; i += 256) {
    const int t = i >> 6, c = i & 63;
    Ul[t][c] = (c0 + c < tc2) ? U12w[t * 226 + c0 + c] : 0.0;
  }
  __syncthreads();

  const int tr  = tid >> 4;          // 0..15 -> rows tr*2 .. +1
  const int tcx = (tid & 15) * 4;    // cols tcx .. +3
  double acc[2][4];
  #pragma unroll
  for (int rr = 0; rr < 2; ++rr) {
    const int rb = rb0 + tr * 2 + rr;
    const int gr = (rb < k0) ? rb : rb + NB;
    #pragma unroll
    for (int c = 0; c < 4; ++c)
      acc[rr][c] = (rb < 225 && (c0 + tcx + c) < tc2)
                 ? A[gr * AP + ct + c0 + tcx + c] : 0.0;
  }
  #pragma unroll
  for (int t = 0; t < NB; ++t) {
    const double p0 = Pl[t][tr * 2], p1 = Pl[t][tr * 2 + 1];
    const double2 u0 = *(const double2*)&Ul[t][tcx];
    const double2 u1 = *(const double2*)&Ul[t][tcx + 2];
    acc[0][0] -= p0 * u0.x; acc[0][1] -= p0 * u0.y;
    acc[0][2] -= p0 * u1.x; acc[0][3] -= p0 * u1.y;
    acc[1][0] -= p1 * u0.x; acc[1][1] -= p1 * u0.y;
    acc[1][2] -= p1 * u1.x; acc[1][3] -= p1 * u1.y;
  }
  #pragma unroll
  for (int rr = 0; rr < 2; ++rr) {
    const int rb = rb0 + tr * 2 + rr;
    const int gr = (rb < k0) ? rb : rb + NB;
    #pragma unroll
    for (int c = 0; c < 4; ++c)
      if (rb < 225 && (c0 + tcx + c) < tc2)
        A[gr * AP + ct + c0 + tcx + c] = acc[rr][c];
  }
}

// ---------------------------------------------------------------------------
// finish: x256 division, then 8 independent per-panel 32-step back-substs
// ---------------------------------------------------------------------------
__global__ __launch_bounds__(256) void finish_kernel(void* __restrict__ wsv) {
  __shared__ double xs[N];
  __shared__ double rr[256];
  double* A   = (double*)((char*)wsv + A_BYTE);
  float*  w0f = (float*)((char*)wsv + W0_BYTE);
  const int tid = threadIdx.x;
  if (tid == 0) xs[256] = A[256 * AP + 257] / A[256 * AP + 256];
  __syncthreads();
  const double x256 = xs[256];
  rr[tid] = A[tid * AP + 257] - A[tid * AP + 256] * x256;
  __syncthreads();
  const int fk0 = tid & ~31;
  const int fs  = tid & 31;
  for (int j = 31; j >= 0; --j) {
    if (fs == j) xs[fk0 + j] = rr[fk0 + j] / A[(fk0 + j) * AP + (fk0 + j)];
    __syncthreads();
    if (fs < j) rr[fk0 + fs] -= A[(fk0 + fs) * AP + (fk0 + j)] * xs[fk0 + j];
    __syncthreads();
  }
  w0f[tid] = (float)xs[tid];
  if (tid == 0) w0f[256] = (float)xs[256];
}

// ---------------------------------------------------------------------------
// combine: out[(b,l), i] = sum_d S[i,d] * W[(b,l), d]
// ---------------------------------------------------------------------------
#define NL 8
__global__ __launch_bounds__(320) void combine_kernel(const float* __restrict__ S,
                                                      const float* __restrict__ om,
                                                      const void* __restrict__ wsv,
                                                      float* __restrict__ out) {
  const int tid = threadIdx.x;
  const int b  = blockIdx.y;
  const int l0 = blockIdx.x * NL;
  const float* w0  = (const float*)((const char*)wsv + W0_BYTE);
  const float* cxy = (const float*)((const char*)wsv + CXY_BYTE);
  __shared__ float Wl[NL][N];
  __shared__ float omsh[2 * MM];
  __shared__ float cxs[NL], cys[NL];

  for (int idx = tid; idx < 2 * MM; idx += 320) omsh[idx] = om[idx];
  if (tid < NL) {
    cxs[tid] = cxy[((size_t)(b * LL) + l0 + tid) * 2];
    cys[tid] = cxy[((size_t)(b * LL) + l0 + tid) * 2 + 1];
  }
  __syncthreads();

  for (int idx = tid; idx < NL * N; idx += 320) {
    const int r = idx / N;
    const int d = idx - r * N;
    float v;
    if (d == 0) {
      v = w0[0];
    } else {
      const int m = (d - 1) >> 1;
      const int pq = 2 * m + 1;
      const float t = cxs[r] * omsh[2 * m] + cys[r] * omsh[2 * m + 1];
      float s, c;
      sincosf(t, &s, &c);
      const float a0 = w0[pq], a1 = w0[pq + 1];
      v = (d & 1) ? (c * a0 - s * a1) : (s * a0 + c * a1);
    }
    Wl[r][d] = v;
  }
  __syncthreads();

  const int i = tid;
  if (i < N) {
    const float* Si = S + (size_t)i * N;
    float acc[NL];
    #pragma unroll
    for (int r = 0; r < NL; ++r) acc[r] = 0.0f;
    #pragma unroll 4
    for (int d = 0; d < N; ++d) {
      const float sv = Si[d];
      #pragma unroll
      for (int r = 0; r < NL; ++r) acc[r] += sv * Wl[r][d];
    }
    const size_t base = (size_t)(b * LL + l0) * N + i;
    #pragma unroll
    for (int r = 0; r < NL; ++r) out[base + (size_t)r * N] = acc[r];
    if (l0 + NL == LL) {
      out[(size_t)BB * LL * N + (size_t)b * N + i] = acc[NL - 1];
    }
  }
}

extern "C" void kernel_launch(void* const* d_in, const int* in_sizes, int n_in,
                              void* d_out, int out_size, void* d_ws, size_t ws_size,
                              hipStream_t stream) {
  const float* x  = (const float*)d_in[0];   // (B, L, 2)
  const float* z0 = (const float*)d_in[1];   // (D,)
  const float* om = (const float*)d_in[2];   // (M, 2)
  const float* S  = (const float*)d_in[3];   // (D, D)
  float* out = (float*)d_out;                // outputs (B,L,D) then z_final (B,D)

  hipLaunchKernelGGL(scan_kernel,  dim3(1),   dim3(512), 0, stream, x, d_ws);
  hipLaunchKernelGGL(stage_kernel, dim3(260), dim3(256), 0, stream, S, z0, d_ws);
  for (int p = 0; p < 8; ++p) {
    const int k0  = p * NB;
    const int tc2 = 258 - (k0 + NB);
    hipLaunchKernelGGL(panel_factor_kernel, dim3(1), dim3(512), 0, stream, d_ws, k0);
    hipLaunchKernelGGL(panel_update_kernel, dim3(8, (tc2 + 63) / 64), dim3(256),
                       0, stream, d_ws, k0, tc2);
  }
  hipLaunchKernelGGL(finish_kernel, dim3(1), dim3(256), 0, stream, d_ws);
  hipLaunchKernelGGL(combine_kernel, dim3(LL / NL, BB), dim3(320), 0, stream, S, om, d_ws, out);
}

// Round 4
// 472.354 us; speedup vs baseline: 1.2306x; 1.0290x over previous
//
#include <hip/hip_runtime.h>
#include <math.h>

#define N    257     // state dim
#define AP   258     // doubles per A row (cols 0..256 = S, col 257 = rhs)
#define MM   128     // rotation pairs
#define LL   512     // seq length
#define BB   4       // batch
#define NB   32      // panel width

// ws byte layout:
#define A_BYTE    0         // double[257*258] = 530448
#define W0_BYTE   530448    // float[257]  -> ends 531476
#define CXY_BYTE  531488    // float[4096] -> ends 547872
#define PW_BYTE   547904    // double[32*257] = 65792 -> ends 613696
#define U12_BYTE  613696    // double[32*226] = 57856 -> ends 671552
#define ST_BYTE   671552    // float[257*257] = 264196 -> ends 935748
// total ~936 KB (ws >= 1.31 MB)

// ---------------------------------------------------------------------------
// prefix sums of x[b,:,comp]: theta[b,l,m] = cx[b,l]*om0[m] + cy[b,l]*om1[m]
// ---------------------------------------------------------------------------
__global__ __launch_bounds__(512) void scan_kernel(const float* __restrict__ x,
                                                   void* __restrict__ wsv) {
  const int tid  = threadIdx.x;
  const int wave = tid >> 6, lane = tid & 63;
  const int b    = wave >> 1, comp = wave & 1;

  const float* xp = x + ((size_t)b * LL) * 2 + comp;
  double loc[8];
  double run = 0.0;
  #pragma unroll
  for (int e = 0; e < 8; ++e) {
    run += (double)xp[(lane * 8 + e) * 2];
    loc[e] = run;
  }
  double tot = run;
  #pragma unroll
  for (int off = 1; off < 64; off <<= 1) {
    const double o = __shfl_up(tot, off);
    if (lane >= off) tot += o;
  }
  const double excl = tot - run;
  float* cp = (float*)((char*)wsv + CXY_BYTE) + ((size_t)b * LL) * 2 + comp;
  #pragma unroll
  for (int e = 0; e < 8; ++e)
    cp[(lane * 8 + e) * 2] = (float)(excl + loc[e]);
}

// ---------------------------------------------------------------------------
// stage A = [S | z0] in fp64, plus St = S^T in fp32 for the combine kernel
// (combine reads St[d*N+i] with i = lane -> coalesced; writing St here is
// coalesced too, the transposed READ of S hits L2).
// ---------------------------------------------------------------------------
__global__ __launch_bounds__(256) void stage_kernel(const float* __restrict__ S,
                                                    const float* __restrict__ z0,
                                                    void* __restrict__ wsv) {
  double* A  = (double*)((char*)wsv + A_BYTE);
  float*  St = (float*)((char*)wsv + ST_BYTE);
  const int idx = blockIdx.x * 256 + threadIdx.x;
  if (idx < N * N) {
    const int i = idx / N, j = idx - i * N;
    A[i * AP + j] = (double)S[idx];
    St[idx] = S[j * N + i];          // St[d][i] = S[i][d]; write coalesced
  } else {
    const int r = idx - N * N;
    if (r < N) A[r * AP + N] = (double)z0[r];
  }
}

// ---------------------------------------------------------------------------
// panel factor: row-parallel Jordan elimination, fully statically unrolled
// (round-3: 49.8us -> <41us; rolled LDS loops paid per-element latency).
// ---------------------------------------------------------------------------
__global__ __launch_bounds__(512) void panel_factor_kernel(void* __restrict__ wsv,
                                                           int k0) {
  __shared__ double P[N][NB + 1];         // 257*33*8 = 67848 B  (panel columns)
  __shared__ double u_s[226][NB + 1];     // 226*33*8 = 59664 B  (U12 columns)
  __shared__ double pinv[NB];
  double* A    = (double*)((char*)wsv + A_BYTE);
  double* Pw   = (double*)((char*)wsv + PW_BYTE);
  double* U12w = (double*)((char*)wsv + U12_BYTE);
  const int tid = threadIdx.x;
  const int ct  = k0 + NB;
  const int tc2 = 258 - ct;               // trailing cols incl rhs

  // ---- stage panel A[0:N, k0:ct) -> P (coalesced double2) ----
  for (int flat = tid; flat < N * 16; flat += 512) {
    const int i  = flat >> 4;
    const int cp = (flat & 15) * 2;
    const double2 v = *(const double2*)&A[(size_t)i * AP + k0 + cp];
    P[i][cp]     = v.x;
    P[i][cp + 1] = v.y;
  }
  // ---- prefetch pivot rows' trailing block -> u_s (own column per thread) ----
  if (tid < tc2) {
    #pragma unroll
    for (int jr = 0; jr < NB; ++jr)
      u_s[tid][jr] = A[(size_t)(k0 + jr) * AP + ct + tid];
  }
  __syncthreads();
  if (tid == 0) pinv[0] = 1.0 / P[k0][0];
  __syncthreads();

  // ---- 32-step row-parallel Jordan elimination, FULLY UNROLLED ----
  #pragma unroll
  for (int j = 0; j < NB; ++j) {
    const int pr = k0 + j;
    if (tid < N && (tid < k0 || tid > pr)) {   // frozen: earlier pivot rows + pr
      const double f = P[tid][j] * pinv[j];
      #pragma unroll
      for (int j2 = j + 1; j2 < NB; ++j2)
        P[tid][j2] -= f * P[pr][j2];
      P[tid][j] = f;
      if (tid == pr + 1 && j + 1 < NB)
        pinv[j + 1] = 1.0 / P[tid][j + 1];     // next pivot's reciprocal, pre-barrier
    }
    __syncthreads();
  }

  // ---- publish factors (all non-pivot rows; pivot-band garbage is unread) ----
  if (tid < N) {
    #pragma unroll
    for (int t = 0; t < NB; ++t)
      Pw[(size_t)t * N + tid] = P[tid][t];
  }
  // ---- publish F11 = L11\U11 block back to A (finish kernel reads U) ----
  for (int flat = tid; flat < NB * NB; flat += 512) {
    const int r = flat >> 5, c = flat & 31;
    A[(size_t)(k0 + r) * AP + k0 + c] = P[k0 + r][c];
  }

  // ---- U12 forward solve: thread owns column tid, FULLY UNROLLED ----
  if (tid < tc2) {
    #pragma unroll
    for (int jr = 1; jr < NB; ++jr) {
      double vv = u_s[tid][jr];
      #pragma unroll
      for (int t = 0; t < jr; ++t)
        vv -= P[k0 + jr][t] * u_s[tid][t];   // P[k0+jr][t<jr] = L11 factors
      u_s[tid][jr] = vv;
    }
    #pragma unroll
    for (int jr = 0; jr < NB; ++jr) {
      const double vv = u_s[tid][jr];
      U12w[jr * 226 + tid] = vv;
      A[(size_t)(k0 + jr) * AP + ct + tid] = vv;
    }
  }
}

// ---------------------------------------------------------------------------
// panel update (grid-parallel Jordan rank-32 GEMM):
//   rows R = [0,k0) U [ct,N)  (225 rows, R-index rb; gr = rb<k0 ? rb : rb+32)
//   cols [ct, 258): A[gr][c] -= sum_t Pw[t][gr] * U12[t][c-ct]
// block tile = 32 rows x 64 cols; thread tile = 2x4.
// ---------------------------------------------------------------------------
__global__ __launch_bounds__(256) void panel_update_kernel(void* __restrict__ wsv,
                                                           int k0, int tc2) {
  __shared__ double Pl[NB][NB + 1];
  __shared__ __align__(16) double Ul[NB][66];
  double* A = (double*)((char*)wsv + A_BYTE);
  const double* Pw   = (const double*)((const char*)wsv + PW_BYTE);
  const double* U12w = (const double*)((const char*)wsv + U12_BYTE);
  const int tid = threadIdx.x;
  const int ct  = k0 + NB;
  const int rb0 = blockIdx.x * 32;
  const int c0  = blockIdx.y * 64;

  for (int i = tid; i < 32 * 32; i += 256) {
    const int t = i >> 5, rr = i & 31;
    const int rb = rb0 + rr;
    const int gr = (rb < k0) ? rb : rb + NB;
    Pl[t][rr] = (rb < 225) ? Pw[t * N + gr] : 0.0;
  }
  for (int i = tid; i < 32 * 64; i += 256) {
    const int t = i >> 6, c = i & 63;
    Ul[t][c] = (c0 + c < tc2) ? U12w[t * 226 + c0 + c] : 0.0;
  }
  __syncthreads();

  const int tr  = tid >> 4;          // 0..15 -> rows tr*2 .. +1
  const int tcx = (tid & 15) * 4;    // cols tcx .. +3
  double acc[2][4];
  #pragma unroll
  for (int rr = 0; rr < 2; ++rr) {
    const int rb = rb0 + tr * 2 + rr;
    const int gr = (rb < k0) ? rb : rb + NB;
    #pragma unroll
    for (int c = 0; c < 4; ++c)
      acc[rr][c] = (rb < 225 && (c0 + tcx + c) < tc2)
                 ? A[gr * AP + ct + c0 + tcx + c] : 0.0;
  }
  #pragma unroll
  for (int t = 0; t < NB; ++t) {
    const double p0 = Pl[t][tr * 2], p1 = Pl[t][tr * 2 + 1];
    const double2 u0 = *(const double2*)&Ul[t][tcx];
    const double2 u1 = *(const double2*)&Ul[t][tcx + 2];
    acc[0][0] -= p0 * u0.x; acc[0][1] -= p0 * u0.y;
    acc[0][2] -= p0 * u1.x; acc[0][3] -= p0 * u1.y;
    acc[1][0] -= p1 * u0.x; acc[1][1] -= p1 * u0.y;
    acc[1][2] -= p1 * u1.x; acc[1][3] -= p1 * u1.y;
  }
  #pragma unroll
  for (int rr = 0; rr < 2; ++rr) {
    const int rb = rb0 + tr * 2 + rr;
    const int gr = (rb < k0) ? rb : rb + NB;
    #pragma unroll
    for (int c = 0; c < 4; ++c)
      if (rb < 225 && (c0 + tcx + c) < tc2)
        A[gr * AP + ct + c0 + tcx + c] = acc[rr][c];
  }
}

// ---------------------------------------------------------------------------
// finish: x256 division, then 8 independent per-panel 32-step back-substs
// ---------------------------------------------------------------------------
__global__ __launch_bounds__(256) void finish_kernel(void* __restrict__ wsv) {
  __shared__ double xs[N];
  __shared__ double rr[256];
  double* A   = (double*)((char*)wsv + A_BYTE);
  float*  w0f = (float*)((char*)wsv + W0_BYTE);
  const int tid = threadIdx.x;
  if (tid == 0) xs[256] = A[256 * AP + 257] / A[256 * AP + 256];
  __syncthreads();
  const double x256 = xs[256];
  rr[tid] = A[tid * AP + 257] - A[tid * AP + 256] * x256;
  __syncthreads();
  const int fk0 = tid & ~31;
  const int fs  = tid & 31;
  for (int j = 31; j >= 0; --j) {
    if (fs == j) xs[fk0 + j] = rr[fk0 + j] / A[(fk0 + j) * AP + (fk0 + j)];
    __syncthreads();
    if (fs < j) rr[fk0 + fs] -= A[(fk0 + fs) * AP + (fk0 + j)] * xs[fk0 + j];
    __syncthreads();
  }
  w0f[tid] = (float)xs[tid];
  if (tid == 0) w0f[256] = (float)xs[256];
}

// ---------------------------------------------------------------------------
// combine: out[(b,l), i] = sum_d St[d, i] * W[(b,l), d]
// Round-4 fix: round-3 counters showed 41.3us, 1% HBM, 12% VALU -> latency
// bound on uncoalesced S reads (lane i read row i of S: 1028B stride across
// the wave, 64 cache lines per wave-load). Now lane i reads St[d*N+i]
// (consecutive addresses), and Wl is transposed to [d][NL] so the broadcast
// operand is two ds_read_b128 per d instead of 8 scalar LDS reads.
// ---------------------------------------------------------------------------
#define NL 8
__global__ __launch_bounds__(320) void combine_kernel(const float* __restrict__ S,
                                                      const float* __restrict__ om,
                                                      const void* __restrict__ wsv,
                                                      float* __restrict__ out) {
  const int tid = threadIdx.x;
  const int b  = blockIdx.y;
  const int l0 = blockIdx.x * NL;
  const float* w0  = (const float*)((const char*)wsv + W0_BYTE);
  const float* cxy = (const float*)((const char*)wsv + CXY_BYTE);
  const float* St  = (const float*)((const char*)wsv + ST_BYTE);
  __shared__ __align__(16) float Wl[N][NL];
  __shared__ float omsh[2 * MM];
  __shared__ float cxs[NL], cys[NL];

  for (int idx = tid; idx < 2 * MM; idx += 320) omsh[idx] = om[idx];
  if (tid < NL) {
    cxs[tid] = cxy[((size_t)(b * LL) + l0 + tid) * 2];
    cys[tid] = cxy[((size_t)(b * LL) + l0 + tid) * 2 + 1];
  }
  __syncthreads();

  for (int idx = tid; idx < NL * N; idx += 320) {
    const int d = idx >> 3;           // state dim 0..256
    const int r = idx & 7;            // l-row within the tile
    float v;
    if (d == 0) {
      v = w0[0];
    } else {
      const int m = (d - 1) >> 1;
      const int pq = 2 * m + 1;
      const float t = cxs[r] * omsh[2 * m] + cys[r] * omsh[2 * m + 1];
      float s, c;
      sincosf(t, &s, &c);
      const float a0 = w0[pq], a1 = w0[pq + 1];
      v = (d & 1) ? (c * a0 - s * a1) : (s * a0 + c * a1);
    }
    Wl[d][r] = v;
  }
  __syncthreads();

  const int i = tid;
  if (i < N) {
    float acc[NL];
    #pragma unroll
    for (int r = 0; r < NL; ++r) acc[r] = 0.0f;
    #pragma unroll 8
    for (int d = 0; d < N; ++d) {
      const float stv = St[(size_t)d * N + i];          // coalesced across lanes
      const float4 wa = *(const float4*)&Wl[d][0];      // broadcast
      const float4 wb = *(const float4*)&Wl[d][4];
      acc[0] += stv * wa.x; acc[1] += stv * wa.y;
      acc[2] += stv * wa.z; acc[3] += stv * wa.w;
      acc[4] += stv * wb.x; acc[5] += stv * wb.y;
      acc[6] += stv * wb.z; acc[7] += stv * wb.w;
    }
    const size_t base = (size_t)(b * LL + l0) * N + i;
    #pragma unroll
    for (int r = 0; r < NL; ++r) out[base + (size_t)r * N] = acc[r];
    if (l0 + NL == LL) {
      out[(size_t)BB * LL * N + (size_t)b * N + i] = acc[NL - 1];
    }
  }
}

extern "C" void kernel_launch(void* const* d_in, const int* in_sizes, int n_in,
                              void* d_out, int out_size, void* d_ws, size_t ws_size,
                              hipStream_t stream) {
  const float* x  = (const float*)d_in[0];   // (B, L, 2)
  const float* z0 = (const float*)d_in[1];   // (D,)
  const float* om = (const float*)d_in[2];   // (M, 2)
  const float* S  = (const float*)d_in[3];   // (D, D)
  float* out = (float*)d_out;                // outputs (B,L,D) then z_final (B,D)

  hipLaunchKernelGGL(scan_kernel,  dim3(1),   dim3(512), 0, stream, x, d_ws);
  hipLaunchKernelGGL(stage_kernel, dim3(260), dim3(256), 0, stream, S, z0, d_ws);
  for (int p = 0; p < 8; ++p) {
    const int k0  = p * NB;
    const int tc2 = 258 - (k0 + NB);
    hipLaunchKernelGGL(panel_factor_kernel, dim3(1), dim3(512), 0, stream, d_ws, k0);
    hipLaunchKernelGGL(panel_update_kernel, dim3(8, (tc2 + 63) / 64), dim3(256),
                       0, stream, d_ws, k0, tc2);
  }
  hipLaunchKernelGGL(finish_kernel, dim3(1), dim3(256), 0, stream, d_ws);
  hipLaunchKernelGGL(combine_kernel, dim3(LL / NL, BB), dim3(320), 0, stream, S, om, d_ws, out);
}